// Round 3
// baseline (823.097 us; speedup 1.0000x reference)
//
#include <hip/hip_runtime.h>

// ICNN_net_1503238553972 — round 3: wave-independent 64-thread blocks (32 rows),
// zero real barriers (__syncthreads == waitcnt for single-wave workgroups).
// Prep kernel converts all weights to f16 into static __device__ g_w16
// (incl. transposed V2z/V3z and Vl1/V2x/V3x for backward). Main kernel:
//   f_hat: layer1 dot2 VALU -> 4x MFMA f16 layers (A-frags from global W16,
//          B-frags/h-tiles in per-wave LDS, XOR-16B-chunk swizzle) -> head dot2.
//   V-net: W-stationary-in-registers GEMVs on v_dot2_f32_f16, z/ga stored f16
//          in per-wave LDS [32][72] (144B stride: 16B-aligned, bank-staggered).
// LDS/block 17408B -> 9 blocks/CU; no cross-wave coupling at all.

typedef _Float16 v2h __attribute__((ext_vector_type(2)));
typedef _Float16 v4h __attribute__((ext_vector_type(4)));
typedef _Float16 v8h __attribute__((ext_vector_type(8)));
typedef float    v4f __attribute__((ext_vector_type(4)));

#define NPTS 500000
#define NBLK (NPTS/32)            // 15625 exact

// offsets in halves inside g_w16
#define OFF_FW    0               // f2..f5: L*16384, [o*128+k]
#define OFF_V2Z   65536           // [j*64+k]
#define OFF_V3Z   69632
#define OFF_V2ZT  73728           // [k*64+j]
#define OFF_V3ZT  77824
#define OFF_VL1T  81920           // [c*64+j]
#define OFF_V2XT  82048
#define OFF_V3XT  82176
#define OFF_VFZ   82304           // [64]
#define OFF_FFW   82368           // [c*128+k]
#define OFF_F1W   82624           // [oc*2+c] (row-major)
#define W16_TOTAL 82880

__device__ __align__(16) _Float16 g_w16[W16_TOTAL];

#if defined(__has_builtin)
#if __has_builtin(__builtin_amdgcn_fdot2)
#define FDOT2(a,b,c) __builtin_amdgcn_fdot2((a),(b),(c),false)
#endif
#endif
#ifndef FDOT2
__device__ __forceinline__ float fdot2_fb(v2h a, v2h b, float c){
  return fmaf((float)a.x, (float)b.x, fmaf((float)a.y, (float)b.y, c));
}
#define FDOT2(a,b,c) fdot2_fb((a),(b),(c))
#endif

__device__ __forceinline__ float srelu(float x){
  float c = fminf(fmaxf(x, 0.f), 1.f);
  return c * fmaf(-0.5f, c, x);
}
__device__ __forceinline__ float sreluD(float x){
  return fminf(fmaxf(x, 0.f), 1.f);
}
__device__ __forceinline__ float lrelu(float x){
  return fmaxf(x, 0.01f * x);
}
__device__ __forceinline__ float sreluD_from_z(float z){
  return fminf(sqrtf(2.f * z), 1.f);
}
__device__ __forceinline__ float dot8(v8h a, v8h b, float s){
  const v2h* ap = (const v2h*)&a;
  const v2h* bp = (const v2h*)&b;
  s = FDOT2(ap[0], bp[0], s);
  s = FDOT2(ap[1], bp[1], s);
  s = FDOT2(ap[2], bp[2], s);
  s = FDOT2(ap[3], bp[3], s);
  return s;
}

// ---------------- prep: fp32 weights -> f16 layouts ----------------
__global__ __launch_bounds__(256) void prep_kernel(
  const float* __restrict__ f2w, const float* __restrict__ f3w,
  const float* __restrict__ f4w, const float* __restrict__ f5w,
  const float* __restrict__ V2z, const float* __restrict__ V3z,
  const float* __restrict__ Vl1, const float* __restrict__ V2x,
  const float* __restrict__ V3x, const float* __restrict__ Vfz,
  const float* __restrict__ ffw, const float* __restrict__ f1w)
{
  const int i = blockIdx.x * 256 + threadIdx.x;
  if (i >= W16_TOTAL) return;
  float v;
  if (i < 65536){
    const float* W[4] = {f2w, f3w, f4w, f5w};
    v = W[i >> 14][i & 16383];
  } else if (i < 69632)  v = V2z[i - 65536];
  else if (i < 73728)    v = V3z[i - 69632];
  else if (i < 77824){ int r = i - 73728; v = V2z[(r & 63)*64 + (r >> 6)]; }
  else if (i < 81920){ int r = i - 77824; v = V3z[(r & 63)*64 + (r >> 6)]; }
  else if (i < 82048){ int r = i - 81920; v = Vl1[(r & 63)*2 + (r >> 6)]; }
  else if (i < 82176){ int r = i - 82048; v = V2x[(r & 63)*2 + (r >> 6)]; }
  else if (i < 82304){ int r = i - 82176; v = V3x[(r & 63)*2 + (r >> 6)]; }
  else if (i < 82368)    v = Vfz[i - 82304];
  else if (i < 82624)    v = ffw[i - 82368];
  else                   v = f1w[i - 82624];
  g_w16[i] = (_Float16)v;
}

// ---------------- f_hat MFMA layer: 128->128, 32 rows ----------------
__device__ __forceinline__ void layer_mfma(const _Float16* hin, _Float16* hout,
    const _Float16* __restrict__ Wl, const float* __restrict__ Bp, int lm, int q)
{
  v4f acc[8][2];
#pragma unroll
  for (int mt = 0; mt < 8; ++mt){
    acc[mt][0] = (v4f){0.f,0.f,0.f,0.f};
    acc[mt][1] = (v4f){0.f,0.f,0.f,0.f};
  }
#pragma unroll
  for (int kt = 0; kt < 4; ++kt){
    const int sw = ((kt*4 + q) ^ lm) << 3;
    v8h B0 = *(const v8h*)(hin + (     lm)*128 + sw);
    v8h B1 = *(const v8h*)(hin + (16 + lm)*128 + sw);
#pragma unroll
    for (int mt = 0; mt < 8; ++mt){
      v8h A = *(const v8h*)(Wl + (mt*16 + lm)*128 + kt*32 + q*8);
      acc[mt][0] = __builtin_amdgcn_mfma_f32_16x16x32_f16(A, B0, acc[mt][0], 0,0,0);
      acc[mt][1] = __builtin_amdgcn_mfma_f32_16x16x32_f16(A, B1, acc[mt][1], 0,0,0);
    }
  }
#pragma unroll
  for (int mt = 0; mt < 8; ++mt){
    const int o0 = mt*16 + q*4;
    const v4f bv = *(const v4f*)(Bp + o0);
    const int coff = (((o0 >> 3) ^ lm) << 3) + (o0 & 7);
#pragma unroll
    for (int nt = 0; nt < 2; ++nt){
      v4h hv;
      hv[0] = (_Float16)lrelu(acc[mt][nt][0] + bv[0]);
      hv[1] = (_Float16)lrelu(acc[mt][nt][1] + bv[1]);
      hv[2] = (_Float16)lrelu(acc[mt][nt][2] + bv[2]);
      hv[3] = (_Float16)lrelu(acc[mt][nt][3] + bv[3]);
      *(v4h*)(hout + (nt*16 + lm)*128 + coff) = hv;
    }
  }
}

// ---------------- V-net GEMVs (W-stationary in regs, dot2) ----------------
__device__ __forceinline__ void vgemv_fwd(const _Float16* zin, _Float16* zout,
    const _Float16* __restrict__ Wrow, float x0, float x1,
    const float* DS, int j)
{
  v8h w[8];
#pragma unroll
  for (int c = 0; c < 8; ++c) w[c] = *(const v8h*)(Wrow + c*8);
#pragma unroll 4
  for (int r = 0; r < 32; ++r){
    float s = fmaf(DS[2*r], x0, DS[2*r+1] * x1);
    const v8h* zp = (const v8h*)(zin + r*72);
#pragma unroll
    for (int c = 0; c < 8; ++c) s = dot8(zp[c], w[c], s);
    zout[r*72 + j] = (_Float16)srelu(s);
  }
}

__device__ __forceinline__ void vgemv_bwd(const _Float16* gin, _Float16* zio,
    const _Float16* __restrict__ WrowT, int k)
{
  v8h w[8];
#pragma unroll
  for (int c = 0; c < 8; ++c) w[c] = *(const v8h*)(WrowT + c*8);
#pragma unroll 4
  for (int r = 0; r < 32; ++r){
    float s = 0.f;
    const v8h* gp = (const v8h*)(gin + r*72);
#pragma unroll
    for (int c = 0; c < 8; ++c) s = dot8(gp[c], w[c], s);
    const float z = (float)zio[r*72 + k];
    zio[r*72 + k] = (_Float16)(s * sreluD_from_z(z));
  }
}

// ---------------- main: one wave = 32 rows, no real barriers ----------------
__global__ __launch_bounds__(64) void icnn_main(
  const float* __restrict__ X, const float* __restrict__ Xst,
  const float* __restrict__ Vfx,
  const float* __restrict__ f1b, const float* __restrict__ f2b,
  const float* __restrict__ f3b, const float* __restrict__ f4b,
  const float* __restrict__ f5b, const float* __restrict__ ffb,
  float* __restrict__ out)
{
  __shared__ __align__(16) char smem[17408];
  _Float16* const HA = (_Float16*)smem;            // [32][128] f16 swizzled
  _Float16* const HB = (_Float16*)(smem + 8192);   // [32][128]
  _Float16* const Z1 = (_Float16*)smem;            // [32][72] f16 (overlay HA)
  _Float16* const Z2 = (_Float16*)(smem + 4608);
  _Float16* const Z3 = (_Float16*)(smem + 9216);
  float* const DS = (float*)(smem + 16384);        // [32][2]
  float* const FH = (float*)(smem + 16640);        // [32][2]
  float* const SF = (float*)(smem + 16896);        // [32]
  float* const VV = (float*)(smem + 17024);        // [32]
  float* const GD = (float*)(smem + 17152);        // [32][2]

  const int t  = threadIdx.x;
  const int b  = blockIdx.x;
  const int lm = t & 15;
  const int q  = t >> 4;

  // P0: d = X - Xstable (500000 = 15625*32 exact; no bounds checks)
  { const int g = b*64 + t; DS[t] = X[g] - Xst[g]; }

  // P1: layer1 (K=2, dot2) -> HA
  {
    const int r = t & 31, hf = t >> 5, rs = r & 15;
    const float2 xv = *(const float2*)(X + (b*32 + r)*2);
    v2h xh; xh.x = (_Float16)xv.x; xh.y = (_Float16)xv.y;
#pragma unroll
    for (int c8 = 0; c8 < 8; ++c8){
      const int c = hf*8 + c8;
      const v4f b0 = *(const v4f*)(f1b + c*8);
      const v4f b1 = *(const v4f*)(f1b + c*8 + 4);
      v8h hv;
#pragma unroll
      for (int jj = 0; jj < 8; ++jj){
        const v2h wv = *(const v2h*)(g_w16 + OFF_F1W + (c*8 + jj)*2);
        const float bb = (jj < 4) ? b0[jj] : b1[jj-4];
        hv[jj] = (_Float16)lrelu(FDOT2(xh, wv, bb));
      }
      *(v8h*)(HA + r*128 + ((c ^ rs) << 3)) = hv;
    }
  }
  __syncthreads();

  // P2: MFMA layers f2..f5 (A-frags from global f16 W)
  layer_mfma(HA, HB, g_w16 + OFF_FW,           f2b, lm, q); __syncthreads();
  layer_mfma(HB, HA, g_w16 + OFF_FW + 16384,   f3b, lm, q); __syncthreads();
  layer_mfma(HA, HB, g_w16 + OFF_FW + 32768,   f4b, lm, q); __syncthreads();
  layer_mfma(HB, HA, g_w16 + OFF_FW + 49152,   f5b, lm, q); __syncthreads();

  // P3: head (h5 in HA)
  {
    const int r = t >> 1, c = t & 1, rs = r & 15;
    float s = ffb[c];
    const v8h* wf = (const v8h*)(g_w16 + OFF_FFW + c*128);
#pragma unroll
    for (int ck = 0; ck < 16; ++ck){
      v8h h = *(const v8h*)(HA + r*128 + ((ck ^ rs) << 3));
      s = dot8(h, wf[ck], s);
    }
    FH[t] = s;
  }
  __syncthreads();

  // P4: z1 = srelu(Vl1 @ d)   (lane = out-channel j)
  {
    const int j = t;
    const float w0 = (float)g_w16[OFF_VL1T + j];
    const float w1 = (float)g_w16[OFF_VL1T + 64 + j];
#pragma unroll 4
    for (int r = 0; r < 32; ++r){
      const float a = fmaf(DS[2*r], w0, DS[2*r+1] * w1);
      Z1[r*72 + j] = (_Float16)srelu(a);
    }
  }
  __syncthreads();

  // P5: z2, z3
  vgemv_fwd(Z1, Z2, g_w16 + OFF_V2Z + t*64,
            (float)g_w16[OFF_V2XT + t], (float)g_w16[OFF_V2XT + 64 + t], DS, t);
  __syncthreads();
  vgemv_fwd(Z2, Z3, g_w16 + OFF_V3Z + t*64,
            (float)g_w16[OFF_V3XT + t], (float)g_w16[OFF_V3XT + 64 + t], DS, t);
  __syncthreads();

  // P6: af, zf, V, sf   (one lane per row)
  if (t < 32){
    const int r = t;
    float s = 0.f;
    const v8h* zp = (const v8h*)(Z3 + r*72);
    const v8h* vf = (const v8h*)(g_w16 + OFF_VFZ);
#pragma unroll
    for (int c = 0; c < 8; ++c) s = dot8(zp[c], vf[c], s);
    const float d0 = DS[2*r], d1 = DS[2*r+1];
    const float af = fmaf(Vfx[0], d0, fmaf(Vfx[1], d1, s));
    const float zf = srelu(af);
    VV[r] = srelu(zf) + 0.01f * fmaf(d0, d0, d1*d1);
    SF[r] = sreluD(zf) * sreluD(af);
  }
  __syncthreads();

  // P7: ga3 = sf * Vfz * srelu'(a3)  (in place over Z3; lane = j)
  {
    const int j = t;
    const float vf = (float)g_w16[OFF_VFZ + j];
#pragma unroll 4
    for (int r = 0; r < 32; ++r){
      const float z = (float)Z3[r*72 + j];
      Z3[r*72 + j] = (_Float16)(SF[r] * vf * sreluD_from_z(z));
    }
  }
  __syncthreads();

  // P8: ga2 = (V3z^T @ ga3) * srelu'(a2)  (in place over Z2; lane = k)
  vgemv_bwd(Z3, Z2, g_w16 + OFF_V3ZT + t*64, t);
  __syncthreads();
  // P9: ga1 = (V2z^T @ ga2) * srelu'(a1)  (in place over Z1)
  vgemv_bwd(Z2, Z1, g_w16 + OFF_V2ZT + t*64, t);
  __syncthreads();

  // P10: gradV  (lane = (row, col))
  {
    const int r = t >> 1, c = t & 1;
    float g = fmaf(0.02f, DS[2*r + c], SF[r] * Vfx[c]);
    const v8h* w1 = (const v8h*)(g_w16 + OFF_VL1T + c*64);
    const v8h* w2 = (const v8h*)(g_w16 + OFF_V2XT + c*64);
    const v8h* w3 = (const v8h*)(g_w16 + OFF_V3XT + c*64);
    const v8h* g1 = (const v8h*)(Z1 + r*72);
    const v8h* g2 = (const v8h*)(Z2 + r*72);
    const v8h* g3 = (const v8h*)(Z3 + r*72);
#pragma unroll
    for (int cc = 0; cc < 8; ++cc){
      g = dot8(g1[cc], w1[cc], g);
      g = dot8(g2[cc], w2[cc], g);
      g = dot8(g3[cc], w3[cc], g);
    }
    GD[t] = g;
  }
  __syncthreads();

  // P11: epilogue
  if (t < 32){
    const float g0 = GD[2*t], g1 = GD[2*t+1];
    const float fh0 = FH[2*t], fh1 = FH[2*t+1];
    const float Vn  = fmaf(g0, g0, g1*g1);
    const float num = fmaf(0.1f, VV[t], fmaf(fh0, g0, fh1*g1));
    const float fm  = fmaxf(num, 0.f) / (Vn + 1e-10f);
    float2 o;
    o.x = fmaf(-g0, fm, fh0);
    o.y = fmaf(-g1, fm, fh1);
    *(float2*)(out + (b*32 + t)*2) = o;
  }
}

extern "C" void kernel_launch(void* const* d_in, const int* in_sizes, int n_in,
                              void* d_out, int out_size, void* d_ws, size_t ws_size,
                              hipStream_t stream)
{
  (void)d_ws; (void)ws_size; (void)n_in; (void)in_sizes; (void)out_size;
  const float* X   = (const float*)d_in[0];
  const float* Xst = (const float*)d_in[1];
  const float* Vl1 = (const float*)d_in[2];
  const float* V2x = (const float*)d_in[3];
  const float* V2z = (const float*)d_in[4];
  const float* V3x = (const float*)d_in[5];
  const float* V3z = (const float*)d_in[6];
  const float* Vfx = (const float*)d_in[7];
  const float* Vfz = (const float*)d_in[8];
  const float* f1w = (const float*)d_in[9];
  const float* f1b = (const float*)d_in[10];
  const float* f2w = (const float*)d_in[11];
  const float* f2b = (const float*)d_in[12];
  const float* f3w = (const float*)d_in[13];
  const float* f3b = (const float*)d_in[14];
  const float* f4w = (const float*)d_in[15];
  const float* f4b = (const float*)d_in[16];
  const float* f5w = (const float*)d_in[17];
  const float* f5b = (const float*)d_in[18];
  const float* ffw = (const float*)d_in[19];
  const float* ffb = (const float*)d_in[20];

  prep_kernel<<<(W16_TOTAL + 255)/256, 256, 0, stream>>>(
      f2w, f3w, f4w, f5w, V2z, V3z, Vl1, V2x, V3x, Vfz, ffw, f1w);
  icnn_main<<<NBLK, 64, 0, stream>>>(
      X, Xst, Vfx, f1b, f2b, f3b, f4b, f5b, ffb, (float*)d_out);
}

// Round 4
// 433.344 us; speedup vs baseline: 1.8994x; 1.8994x over previous
//
#include <hip/hip_runtime.h>

// ICNN_net_1503238553972 — round 4: 256-thread/64-row blocks, occupancy-first.
// prep kernel: all weights -> f16 in g_w16 (MFMA A-frags read straight from
// L2; incl. transposed V-weights for backward). Main kernel LDS = 34 KB ->
// 4 blocks/CU; __launch_bounds__(256,4) caps VGPR at 128 -> 16 waves/CU.
// Only 6 block-wide barriers: layer1, f2..f5, head. The entire V phase is
// wave-private (wave w owns rows 16w..16w+16): z/ga GEMVs on v_dot2_f32_f16,
// z f16 in LDS [64][72], per-wave head/DS/SF/VV/GD/epilogue — no barriers.

typedef _Float16 v2h __attribute__((ext_vector_type(2)));
typedef _Float16 v4h __attribute__((ext_vector_type(4)));
typedef _Float16 v8h __attribute__((ext_vector_type(8)));
typedef float    v4f __attribute__((ext_vector_type(4)));

#define NPTS 500000
#define NBLK ((NPTS + 63) / 64)   // 7813

// offsets in halves inside g_w16
#define OFF_FW    0               // f2..f5: L*16384, [o*128+k]
#define OFF_V2Z   65536           // [j*64+k]
#define OFF_V3Z   69632
#define OFF_V2ZT  73728           // [k*64+j]
#define OFF_V3ZT  77824
#define OFF_VL1T  81920           // [c*64+j]
#define OFF_V2XT  82048
#define OFF_V3XT  82176
#define OFF_VFZ   82304           // [64]
#define OFF_FFW   82368           // [c*128+k]
#define OFF_F1W   82624           // [oc*2+c]
#define W16_TOTAL 82880

__device__ __align__(16) _Float16 g_w16[W16_TOTAL];

#if defined(__has_builtin)
#if __has_builtin(__builtin_amdgcn_fdot2)
#define FDOT2(a,b,c) __builtin_amdgcn_fdot2((a),(b),(c),false)
#endif
#endif
#ifndef FDOT2
__device__ __forceinline__ float fdot2_fb(v2h a, v2h b, float c){
  return fmaf((float)a.x, (float)b.x, fmaf((float)a.y, (float)b.y, c));
}
#define FDOT2(a,b,c) fdot2_fb((a),(b),(c))
#endif

__device__ __forceinline__ float srelu(float x){
  float c = fminf(fmaxf(x, 0.f), 1.f);
  return c * fmaf(-0.5f, c, x);
}
__device__ __forceinline__ float sreluD(float x){
  return fminf(fmaxf(x, 0.f), 1.f);
}
__device__ __forceinline__ float lrelu(float x){
  return fmaxf(x, 0.01f * x);
}
__device__ __forceinline__ float sreluD_from_z(float z){
  return fminf(sqrtf(2.f * z), 1.f);
}
__device__ __forceinline__ float dot8(v8h a, v8h b, float s){
  const v2h* ap = (const v2h*)&a;
  const v2h* bp = (const v2h*)&b;
  s = FDOT2(ap[0], bp[0], s);
  s = FDOT2(ap[1], bp[1], s);
  s = FDOT2(ap[2], bp[2], s);
  s = FDOT2(ap[3], bp[3], s);
  return s;
}

// ---------------- prep: fp32 weights -> f16 layouts ----------------
__global__ __launch_bounds__(256) void prep_kernel(
  const float* __restrict__ f2w, const float* __restrict__ f3w,
  const float* __restrict__ f4w, const float* __restrict__ f5w,
  const float* __restrict__ V2z, const float* __restrict__ V3z,
  const float* __restrict__ Vl1, const float* __restrict__ V2x,
  const float* __restrict__ V3x, const float* __restrict__ Vfz,
  const float* __restrict__ ffw, const float* __restrict__ f1w)
{
  const int i = blockIdx.x * 256 + threadIdx.x;
  if (i >= W16_TOTAL) return;
  float v;
  if (i < 65536){
    const float* W[4] = {f2w, f3w, f4w, f5w};
    v = W[i >> 14][i & 16383];
  } else if (i < 69632)  v = V2z[i - 65536];
  else if (i < 73728)    v = V3z[i - 69632];
  else if (i < 77824){ int r = i - 73728; v = V2z[(r & 63)*64 + (r >> 6)]; }
  else if (i < 81920){ int r = i - 77824; v = V3z[(r & 63)*64 + (r >> 6)]; }
  else if (i < 82048){ int r = i - 81920; v = Vl1[(r & 63)*2 + (r >> 6)]; }
  else if (i < 82176){ int r = i - 82048; v = V2x[(r & 63)*2 + (r >> 6)]; }
  else if (i < 82304){ int r = i - 82176; v = V3x[(r & 63)*2 + (r >> 6)]; }
  else if (i < 82368)    v = Vfz[i - 82304];
  else if (i < 82624)    v = ffw[i - 82368];
  else                   v = f1w[i - 82624];
  g_w16[i] = (_Float16)v;
}

// ---------------- f_hat MFMA layer: 128->128, 64 rows, wave=32 out-ch ----------------
__device__ __forceinline__ void layer_mfma(const _Float16* hin, _Float16* hout,
    const _Float16* __restrict__ Wl, const float* __restrict__ Bp,
    int w, int lm, int q)
{
  v4f acc[2][4];
#pragma unroll
  for (int mt = 0; mt < 2; ++mt)
#pragma unroll
    for (int nt = 0; nt < 4; ++nt) acc[mt][nt] = (v4f){0.f,0.f,0.f,0.f};

#pragma unroll
  for (int kt = 0; kt < 4; ++kt){
    const int sw = ((kt*4 + q) ^ lm) << 3;
    v8h A0 = *(const v8h*)(Wl + (w*32      + lm)*128 + kt*32 + q*8);
    v8h A1 = *(const v8h*)(Wl + (w*32 + 16 + lm)*128 + kt*32 + q*8);
    v8h B0 = *(const v8h*)(hin + (     lm)*128 + sw);
    v8h B1 = *(const v8h*)(hin + (16 + lm)*128 + sw);
    v8h B2 = *(const v8h*)(hin + (32 + lm)*128 + sw);
    v8h B3 = *(const v8h*)(hin + (48 + lm)*128 + sw);
    acc[0][0] = __builtin_amdgcn_mfma_f32_16x16x32_f16(A0, B0, acc[0][0], 0,0,0);
    acc[0][1] = __builtin_amdgcn_mfma_f32_16x16x32_f16(A0, B1, acc[0][1], 0,0,0);
    acc[0][2] = __builtin_amdgcn_mfma_f32_16x16x32_f16(A0, B2, acc[0][2], 0,0,0);
    acc[0][3] = __builtin_amdgcn_mfma_f32_16x16x32_f16(A0, B3, acc[0][3], 0,0,0);
    acc[1][0] = __builtin_amdgcn_mfma_f32_16x16x32_f16(A1, B0, acc[1][0], 0,0,0);
    acc[1][1] = __builtin_amdgcn_mfma_f32_16x16x32_f16(A1, B1, acc[1][1], 0,0,0);
    acc[1][2] = __builtin_amdgcn_mfma_f32_16x16x32_f16(A1, B2, acc[1][2], 0,0,0);
    acc[1][3] = __builtin_amdgcn_mfma_f32_16x16x32_f16(A1, B3, acc[1][3], 0,0,0);
  }

#pragma unroll
  for (int mt = 0; mt < 2; ++mt){
    const int o0 = w*32 + mt*16 + q*4;
    const v4f bv = *(const v4f*)(Bp + o0);
    const int coff = (((o0 >> 3) ^ lm) << 3) + (o0 & 7);
#pragma unroll
    for (int nt = 0; nt < 4; ++nt){
      const int r = nt*16 + lm;
      v4h hv;
      hv[0] = (_Float16)lrelu(acc[mt][nt][0] + bv[0]);
      hv[1] = (_Float16)lrelu(acc[mt][nt][1] + bv[1]);
      hv[2] = (_Float16)lrelu(acc[mt][nt][2] + bv[2]);
      hv[3] = (_Float16)lrelu(acc[mt][nt][3] + bv[3]);
      *(v4h*)(hout + r*128 + coff) = hv;
    }
  }
}

// ---------------- V-net GEMVs (wave-private 16 rows, lane=channel) ----------------
__device__ __forceinline__ void vgemv_fwd(const _Float16* zin, _Float16* zout,
    const _Float16* __restrict__ Wrow, float x0, float x1,
    const float* DS, int j, int r0)
{
  v8h wv[8];
#pragma unroll
  for (int c = 0; c < 8; ++c) wv[c] = *(const v8h*)(Wrow + c*8);
#pragma unroll 4
  for (int rr = 0; rr < 16; ++rr){
    const int r = r0 + rr;
    float s = fmaf(DS[2*r], x0, DS[2*r+1] * x1);
    const v8h* zp = (const v8h*)(zin + r*72);
#pragma unroll
    for (int c = 0; c < 8; ++c) s = dot8(zp[c], wv[c], s);
    zout[r*72 + j] = (_Float16)srelu(s);
  }
}

__device__ __forceinline__ void vgemv_bwd(const _Float16* gin, _Float16* zio,
    const _Float16* __restrict__ WrowT, int k, int r0)
{
  v8h wv[8];
#pragma unroll
  for (int c = 0; c < 8; ++c) wv[c] = *(const v8h*)(WrowT + c*8);
#pragma unroll 4
  for (int rr = 0; rr < 16; ++rr){
    const int r = r0 + rr;
    float s = 0.f;
    const v8h* gp = (const v8h*)(gin + r*72);
#pragma unroll
    for (int c = 0; c < 8; ++c) s = dot8(gp[c], wv[c], s);
    const float z = (float)zio[r*72 + k];
    zio[r*72 + k] = (_Float16)(s * sreluD_from_z(z));
  }
}

// ---------------- main ----------------
__global__ __launch_bounds__(256, 4) void icnn_main(
  const float* __restrict__ X, const float* __restrict__ Xst,
  const float* __restrict__ Vfx,
  const float* __restrict__ f1b, const float* __restrict__ f2b,
  const float* __restrict__ f3b, const float* __restrict__ f4b,
  const float* __restrict__ f5b, const float* __restrict__ ffb,
  float* __restrict__ out)
{
  __shared__ __align__(16) char smem[34816];
  _Float16* const HA = (_Float16*)smem;             // [64][128] f16 swizzled
  _Float16* const HB = (_Float16*)(smem + 16384);   // [64][128]
  _Float16* const Z1 = (_Float16*)smem;             // [64][72] f16 (overlays HA)
  _Float16* const Z2 = (_Float16*)(smem + 9216);
  _Float16* const Z3 = (_Float16*)(smem + 18432);
  float* const DS = (float*)(smem + 32768);         // [64][2]
  float* const FH = (float*)(smem + 33280);         // [64][2]
  float* const SF = (float*)(smem + 33792);         // [64]
  float* const VV = (float*)(smem + 34048);         // [64]
  float* const GD = (float*)(smem + 34304);         // [64][2]

  const int t  = threadIdx.x;
  const int b  = blockIdx.x;
  const int w  = t >> 6;        // wave id
  const int l  = t & 63;        // lane in wave
  const int lm = l & 15;
  const int q  = l >> 4;
  const int r0 = w * 16;        // this wave's 16 V-phase rows

  // ---- P1: layer1 (K=2, dot2) -> HA ----
  {
    const int tx = t & 15, ty = t >> 4;   // rows tx+16i, cols ty*8..
    v2h wv[8]; float bb[8];
#pragma unroll
    for (int j = 0; j < 8; ++j){
      wv[j] = *(const v2h*)(g_w16 + OFF_F1W + (ty*8 + j)*2);
      bb[j] = f1b[ty*8 + j];
    }
#pragma unroll
    for (int i = 0; i < 4; ++i){
      const int r = tx + 16*i;
      int g = b*64 + r; if (g > NPTS-1) g = NPTS-1;
      const float2 xv = *(const float2*)(X + g*2);
      v2h xh; xh.x = (_Float16)xv.x; xh.y = (_Float16)xv.y;
      v8h hv;
#pragma unroll
      for (int j = 0; j < 8; ++j)
        hv[j] = (_Float16)lrelu(FDOT2(xh, wv[j], bb[j]));
      *(v8h*)(HA + r*128 + ((ty ^ (r & 15)) << 3)) = hv;
    }
  }
  __syncthreads();  // B1

  // ---- P2: MFMA layers f2..f5 (A from global g_w16) ----
  layer_mfma(HA, HB, g_w16 + OFF_FW,         f2b, w, lm, q); __syncthreads(); // B2
  layer_mfma(HB, HA, g_w16 + OFF_FW + 16384, f3b, w, lm, q); __syncthreads(); // B3
  layer_mfma(HA, HB, g_w16 + OFF_FW + 32768, f4b, w, lm, q); __syncthreads(); // B4
  layer_mfma(HB, HA, g_w16 + OFF_FW + 49152, f5b, w, lm, q); __syncthreads(); // B5

  // ---- P3: per-wave head (rows r0..r0+16) + DS staging ----
  if (l < 32){
    const int r = r0 + (l >> 1), c = l & 1, rs = r & 15;
    float s = ffb[c];
    const v8h* wf = (const v8h*)(g_w16 + OFF_FFW + c*128);
#pragma unroll
    for (int ck = 0; ck < 16; ++ck){
      v8h h = *(const v8h*)(HA + r*128 + ((ck ^ rs) << 3));
      s = dot8(h, wf[ck], s);
    }
    FH[r*2 + c] = s;
  } else {
    const int idx = w*32 + (l - 32);            // DS entries for rows r0..r0+16
    int g = b*128 + idx; if (g > 2*NPTS-1) g = 2*NPTS-1;
    DS[idx] = X[g] - Xst[g];
  }
  __syncthreads();  // B6 — last barrier; Z buffers overlay HA/HB below

  // ================= V phase: fully wave-private =================
  const int j = l;

  // P4: z1 = srelu(Vl1 @ d)
  {
    const float w0 = (float)g_w16[OFF_VL1T + j];
    const float w1 = (float)g_w16[OFF_VL1T + 64 + j];
#pragma unroll 4
    for (int rr = 0; rr < 16; ++rr){
      const int r = r0 + rr;
      const float a = fmaf(DS[2*r], w0, DS[2*r+1] * w1);
      Z1[r*72 + j] = (_Float16)srelu(a);
    }
  }

  // P5: z2, z3
  vgemv_fwd(Z1, Z2, g_w16 + OFF_V2Z + j*64,
            (float)g_w16[OFF_V2XT + j], (float)g_w16[OFF_V2XT + 64 + j], DS, j, r0);
  vgemv_fwd(Z2, Z3, g_w16 + OFF_V3Z + j*64,
            (float)g_w16[OFF_V3XT + j], (float)g_w16[OFF_V3XT + 64 + j], DS, j, r0);

  // P6: af, zf, V, sf  (lane per row)
  if (l < 16){
    const int r = r0 + l;
    float s = 0.f;
    const v8h* zp = (const v8h*)(Z3 + r*72);
    const v8h* vf = (const v8h*)(g_w16 + OFF_VFZ);
#pragma unroll
    for (int c = 0; c < 8; ++c) s = dot8(zp[c], vf[c], s);
    const float d0 = DS[2*r], d1 = DS[2*r+1];
    const float af = fmaf(Vfx[0], d0, fmaf(Vfx[1], d1, s));
    const float zf = srelu(af);
    VV[r] = srelu(zf) + 0.01f * fmaf(d0, d0, d1*d1);
    SF[r] = sreluD(zf) * sreluD(af);
  }

  // P7: ga3 = sf * Vfz * srelu'(a3)  (in place over Z3)
  {
    const float vf = (float)g_w16[OFF_VFZ + j];
#pragma unroll 4
    for (int rr = 0; rr < 16; ++rr){
      const int r = r0 + rr;
      const float z = (float)Z3[r*72 + j];
      Z3[r*72 + j] = (_Float16)(SF[r] * vf * sreluD_from_z(z));
    }
  }

  // P8/P9: backward GEMVs (in place)
  vgemv_bwd(Z3, Z2, g_w16 + OFF_V3ZT + j*64, j, r0);
  vgemv_bwd(Z2, Z1, g_w16 + OFF_V2ZT + j*64, j, r0);

  // P10: gradV  (2 lanes per row)
  if (l < 32){
    const int r = r0 + (l >> 1), c = l & 1;
    float g = fmaf(0.02f, DS[2*r + c], SF[r] * Vfx[c]);
    const v8h* w1 = (const v8h*)(g_w16 + OFF_VL1T + c*64);
    const v8h* w2 = (const v8h*)(g_w16 + OFF_V2XT + c*64);
    const v8h* w3 = (const v8h*)(g_w16 + OFF_V3XT + c*64);
    const v8h* g1 = (const v8h*)(Z1 + r*72);
    const v8h* g2 = (const v8h*)(Z2 + r*72);
    const v8h* g3 = (const v8h*)(Z3 + r*72);
#pragma unroll
    for (int cc = 0; cc < 8; ++cc){
      g = dot8(g1[cc], w1[cc], g);
      g = dot8(g2[cc], w2[cc], g);
      g = dot8(g3[cc], w3[cc], g);
    }
    GD[r*2 + c] = g;
  }

  // P11: epilogue (lane per row)
  if (l < 16){
    const int r = r0 + l;
    const int row = b*64 + r;
    if (row < NPTS){
      const float g0 = GD[2*r], g1 = GD[2*r+1];
      const float fh0 = FH[2*r], fh1 = FH[2*r+1];
      const float Vn  = fmaf(g0, g0, g1*g1);
      const float num = fmaf(0.1f, VV[r], fmaf(fh0, g0, fh1*g1));
      const float fm  = fmaxf(num, 0.f) / (Vn + 1e-10f);
      float2 o;
      o.x = fmaf(-g0, fm, fh0);
      o.y = fmaf(-g1, fm, fh1);
      *(float2*)(out + row*2) = o;
    }
  }
}

extern "C" void kernel_launch(void* const* d_in, const int* in_sizes, int n_in,
                              void* d_out, int out_size, void* d_ws, size_t ws_size,
                              hipStream_t stream)
{
  (void)d_ws; (void)ws_size; (void)n_in; (void)in_sizes; (void)out_size;
  const float* X   = (const float*)d_in[0];
  const float* Xst = (const float*)d_in[1];
  const float* Vl1 = (const float*)d_in[2];
  const float* V2x = (const float*)d_in[3];
  const float* V2z = (const float*)d_in[4];
  const float* V3x = (const float*)d_in[5];
  const float* V3z = (const float*)d_in[6];
  const float* Vfx = (const float*)d_in[7];
  const float* Vfz = (const float*)d_in[8];
  const float* f1w = (const float*)d_in[9];
  const float* f1b = (const float*)d_in[10];
  const float* f2w = (const float*)d_in[11];
  const float* f2b = (const float*)d_in[12];
  const float* f3w = (const float*)d_in[13];
  const float* f3b = (const float*)d_in[14];
  const float* f4w = (const float*)d_in[15];
  const float* f4b = (const float*)d_in[16];
  const float* f5w = (const float*)d_in[17];
  const float* f5b = (const float*)d_in[18];
  const float* ffw = (const float*)d_in[19];
  const float* ffb = (const float*)d_in[20];

  prep_kernel<<<(W16_TOTAL + 255)/256, 256, 0, stream>>>(
      f2w, f3w, f4w, f5w, V2z, V3z, Vl1, V2x, V3x, Vfz, ffw, f1w);
  icnn_main<<<NBLK, 256, 0, stream>>>(
      X, Xst, Vfx, f1b, f2b, f3b, f4b, f5b, ffb, (float*)d_out);
}

// Round 5
// 410.855 us; speedup vs baseline: 2.0034x; 1.0547x over previous
//
#include <hip/hip_runtime.h>

// ICNN_net_1503238553972 — round 5: round-4 structure (256 thr / 64 rows,
// 6 barriers, wave-private V phase) + V-network 64x64 GEMMs on wave-private
// MFMA. Per wave: 16 rows; fwd z2/z3 and bwd ga2/ga1 are each
// 4 m-tiles x 2 k-steps of mfma_f32_16x16x32_f16. B-frags from wave-private
// LDS z-buffers ([r][64] f16, XOR-8-chunk swizzle, 2-way max); A-frags from
// L2-hot g_w16 (incl. transposed W for backward). D-layout epilogue writes
// (4 consecutive out-ch per lane = 8B) land exactly in next layer's B-frag
// layout; bwd srelu'(z) gather is an 8B lane-local read-modify-write.

typedef _Float16 v2h __attribute__((ext_vector_type(2)));
typedef _Float16 v4h __attribute__((ext_vector_type(4)));
typedef _Float16 v8h __attribute__((ext_vector_type(8)));
typedef float    v4f __attribute__((ext_vector_type(4)));

#define NPTS 500000
#define NBLK ((NPTS + 63) / 64)   // 7813

// offsets in halves inside g_w16
#define OFF_FW    0               // f2..f5: L*16384, [o*128+k]
#define OFF_V2Z   65536           // [j*64+k]
#define OFF_V3Z   69632
#define OFF_V2ZT  73728           // [k*64+j]
#define OFF_V3ZT  77824
#define OFF_VL1T  81920           // [c*64+j]
#define OFF_V2XT  82048
#define OFF_V3XT  82176
#define OFF_VFZ   82304           // [64]
#define OFF_FFW   82368           // [c*128+k]
#define OFF_F1W   82624           // [oc*2+c]
#define W16_TOTAL 82880

__device__ __align__(16) _Float16 g_w16[W16_TOTAL];

#if defined(__has_builtin)
#if __has_builtin(__builtin_amdgcn_fdot2)
#define FDOT2(a,b,c) __builtin_amdgcn_fdot2((a),(b),(c),false)
#endif
#endif
#ifndef FDOT2
__device__ __forceinline__ float fdot2_fb(v2h a, v2h b, float c){
  return fmaf((float)a.x, (float)b.x, fmaf((float)a.y, (float)b.y, c));
}
#define FDOT2(a,b,c) fdot2_fb((a),(b),(c))
#endif

__device__ __forceinline__ float srelu(float x){
  float c = fminf(fmaxf(x, 0.f), 1.f);
  return c * fmaf(-0.5f, c, x);
}
__device__ __forceinline__ float sreluD(float x){
  return fminf(fmaxf(x, 0.f), 1.f);
}
__device__ __forceinline__ float lrelu(float x){
  return fmaxf(x, 0.01f * x);
}
__device__ __forceinline__ float sreluD_from_z(float z){
  return fminf(sqrtf(2.f * z), 1.f);
}
__device__ __forceinline__ float dot8(v8h a, v8h b, float s){
  const v2h* ap = (const v2h*)&a;
  const v2h* bp = (const v2h*)&b;
  s = FDOT2(ap[0], bp[0], s);
  s = FDOT2(ap[1], bp[1], s);
  s = FDOT2(ap[2], bp[2], s);
  s = FDOT2(ap[3], bp[3], s);
  return s;
}

// ---------------- prep: fp32 weights -> f16 layouts ----------------
__global__ __launch_bounds__(256) void prep_kernel(
  const float* __restrict__ f2w, const float* __restrict__ f3w,
  const float* __restrict__ f4w, const float* __restrict__ f5w,
  const float* __restrict__ V2z, const float* __restrict__ V3z,
  const float* __restrict__ Vl1, const float* __restrict__ V2x,
  const float* __restrict__ V3x, const float* __restrict__ Vfz,
  const float* __restrict__ ffw, const float* __restrict__ f1w)
{
  const int i = blockIdx.x * 256 + threadIdx.x;
  if (i >= W16_TOTAL) return;
  float v;
  if (i < 65536){
    const float* W[4] = {f2w, f3w, f4w, f5w};
    v = W[i >> 14][i & 16383];
  } else if (i < 69632)  v = V2z[i - 65536];
  else if (i < 73728)    v = V3z[i - 69632];
  else if (i < 77824){ int r = i - 73728; v = V2z[(r & 63)*64 + (r >> 6)]; }
  else if (i < 81920){ int r = i - 77824; v = V3z[(r & 63)*64 + (r >> 6)]; }
  else if (i < 82048){ int r = i - 81920; v = Vl1[(r & 63)*2 + (r >> 6)]; }
  else if (i < 82176){ int r = i - 82048; v = V2x[(r & 63)*2 + (r >> 6)]; }
  else if (i < 82304){ int r = i - 82176; v = V3x[(r & 63)*2 + (r >> 6)]; }
  else if (i < 82368)    v = Vfz[i - 82304];
  else if (i < 82624)    v = ffw[i - 82368];
  else                   v = f1w[i - 82624];
  g_w16[i] = (_Float16)v;
}

// ---------------- f_hat MFMA layer: 128->128, 64 rows, wave=32 out-ch ----------------
__device__ __forceinline__ void layer_mfma(const _Float16* hin, _Float16* hout,
    const _Float16* __restrict__ Wl, const float* __restrict__ Bp,
    int w, int lm, int q)
{
  v4f acc[2][4];
#pragma unroll
  for (int mt = 0; mt < 2; ++mt)
#pragma unroll
    for (int nt = 0; nt < 4; ++nt) acc[mt][nt] = (v4f){0.f,0.f,0.f,0.f};

#pragma unroll
  for (int kt = 0; kt < 4; ++kt){
    const int sw = ((kt*4 + q) ^ lm) << 3;
    v8h A0 = *(const v8h*)(Wl + (w*32      + lm)*128 + kt*32 + q*8);
    v8h A1 = *(const v8h*)(Wl + (w*32 + 16 + lm)*128 + kt*32 + q*8);
    v8h B0 = *(const v8h*)(hin + (     lm)*128 + sw);
    v8h B1 = *(const v8h*)(hin + (16 + lm)*128 + sw);
    v8h B2 = *(const v8h*)(hin + (32 + lm)*128 + sw);
    v8h B3 = *(const v8h*)(hin + (48 + lm)*128 + sw);
    acc[0][0] = __builtin_amdgcn_mfma_f32_16x16x32_f16(A0, B0, acc[0][0], 0,0,0);
    acc[0][1] = __builtin_amdgcn_mfma_f32_16x16x32_f16(A0, B1, acc[0][1], 0,0,0);
    acc[0][2] = __builtin_amdgcn_mfma_f32_16x16x32_f16(A0, B2, acc[0][2], 0,0,0);
    acc[0][3] = __builtin_amdgcn_mfma_f32_16x16x32_f16(A0, B3, acc[0][3], 0,0,0);
    acc[1][0] = __builtin_amdgcn_mfma_f32_16x16x32_f16(A1, B0, acc[1][0], 0,0,0);
    acc[1][1] = __builtin_amdgcn_mfma_f32_16x16x32_f16(A1, B1, acc[1][1], 0,0,0);
    acc[1][2] = __builtin_amdgcn_mfma_f32_16x16x32_f16(A1, B2, acc[1][2], 0,0,0);
    acc[1][3] = __builtin_amdgcn_mfma_f32_16x16x32_f16(A1, B3, acc[1][3], 0,0,0);
  }

#pragma unroll
  for (int mt = 0; mt < 2; ++mt){
    const int o0 = w*32 + mt*16 + q*4;
    const v4f bv = *(const v4f*)(Bp + o0);
    const int coff = (((o0 >> 3) ^ lm) << 3) + (o0 & 7);
#pragma unroll
    for (int nt = 0; nt < 4; ++nt){
      const int r = nt*16 + lm;
      v4h hv;
      hv[0] = (_Float16)lrelu(acc[mt][nt][0] + bv[0]);
      hv[1] = (_Float16)lrelu(acc[mt][nt][1] + bv[1]);
      hv[2] = (_Float16)lrelu(acc[mt][nt][2] + bv[2]);
      hv[3] = (_Float16)lrelu(acc[mt][nt][3] + bv[3]);
      *(v4h*)(hout + r*128 + coff) = hv;
    }
  }
}

// ---------------- V-net fwd layer (wave-private MFMA, 16 rows) ----------------
// zout[r][o] = srelu( sum_k Wz[o][k] zin[r][k] + Wx[o][0]*d0 + Wx[o][1]*d1 )
__device__ __forceinline__ void vfwd_mfma(const _Float16* zin, _Float16* zout,
    const _Float16* __restrict__ Wz,   // [64][64] row-major
    const _Float16* __restrict__ WxT,  // [2][64]
    const float* DS, int r0, int lm, int q)
{
  v4f acc[4];
#pragma unroll
  for (int mt = 0; mt < 4; ++mt) acc[mt] = (v4f){0.f,0.f,0.f,0.f};
  const int rs = lm & 7;
#pragma unroll
  for (int kt = 0; kt < 2; ++kt){
    v8h B = *(const v8h*)(zin + (r0 + lm)*64 + (((kt*4 + q) ^ rs) << 3));
#pragma unroll
    for (int mt = 0; mt < 4; ++mt){
      v8h A = *(const v8h*)(Wz + (mt*16 + lm)*64 + kt*32 + q*8);
      acc[mt] = __builtin_amdgcn_mfma_f32_16x16x32_f16(A, B, acc[mt], 0,0,0);
    }
  }
  const float d0 = DS[2*(r0+lm)], d1 = DS[2*(r0+lm)+1];
#pragma unroll
  for (int mt = 0; mt < 4; ++mt){
    const int o0 = mt*16 + q*4;
    v4h hv;
#pragma unroll
    for (int reg = 0; reg < 4; ++reg){
      const int o = o0 + reg;
      const float v = acc[mt][reg]
                    + (float)WxT[o]*d0 + (float)WxT[64 + o]*d1;
      hv[reg] = (_Float16)srelu(v);
    }
    *(v4h*)(zout + (r0 + lm)*64 + (((o0 >> 3) ^ rs) << 3) + (o0 & 7)) = hv;
  }
}

// ---------------- V-net bwd layer (wave-private MFMA, in-place) ----------------
// zio[r][k] = ( sum_j WT[k][j] gin[r][j] ) * srelu'_from_z( zio[r][k] )
__device__ __forceinline__ void vbwd_mfma(const _Float16* gin, _Float16* zio,
    const _Float16* __restrict__ WT,   // [64][64] = W^T row-major [k][j]
    int r0, int lm, int q)
{
  v4f acc[4];
#pragma unroll
  for (int mt = 0; mt < 4; ++mt) acc[mt] = (v4f){0.f,0.f,0.f,0.f};
  const int rs = lm & 7;
#pragma unroll
  for (int kt = 0; kt < 2; ++kt){
    v8h B = *(const v8h*)(gin + (r0 + lm)*64 + (((kt*4 + q) ^ rs) << 3));
#pragma unroll
    for (int mt = 0; mt < 4; ++mt){
      v8h A = *(const v8h*)(WT + (mt*16 + lm)*64 + kt*32 + q*8);
      acc[mt] = __builtin_amdgcn_mfma_f32_16x16x32_f16(A, B, acc[mt], 0,0,0);
    }
  }
#pragma unroll
  for (int mt = 0; mt < 4; ++mt){
    const int k0 = mt*16 + q*4;
    _Float16* p = zio + (r0 + lm)*64 + (((k0 >> 3) ^ rs) << 3) + (k0 & 7);
    v4h zv = *(const v4h*)p;
    v4h gv;
#pragma unroll
    for (int reg = 0; reg < 4; ++reg)
      gv[reg] = (_Float16)(acc[mt][reg] * sreluD_from_z((float)zv[reg]));
    *(v4h*)p = gv;
  }
}

// ---------------- main ----------------
__global__ __launch_bounds__(256, 4) void icnn_main(
  const float* __restrict__ X, const float* __restrict__ Xst,
  const float* __restrict__ Vfx,
  const float* __restrict__ f1b, const float* __restrict__ f2b,
  const float* __restrict__ f3b, const float* __restrict__ f4b,
  const float* __restrict__ f5b, const float* __restrict__ ffb,
  float* __restrict__ out)
{
  __shared__ __align__(16) char smem[34816];
  _Float16* const HA = (_Float16*)smem;             // [64][128] f16 swizzled(16)
  _Float16* const HB = (_Float16*)(smem + 16384);   // [64][128]
  _Float16* const Z1 = (_Float16*)smem;             // [64][64] f16 swz(8) (overlay HA)
  _Float16* const Z2 = (_Float16*)(smem + 8192);    // [64][64] (overlay HA hi)
  _Float16* const Z3 = (_Float16*)(smem + 16384);   // [64][64] (overlay HB lo)
  float* const DS = (float*)(smem + 32768);         // [64][2]
  float* const FH = (float*)(smem + 33280);         // [64][2]
  float* const SF = (float*)(smem + 33792);         // [64]
  float* const VV = (float*)(smem + 34048);         // [64]
  float* const GD = (float*)(smem + 34304);         // [64][2]

  const int t  = threadIdx.x;
  const int b  = blockIdx.x;
  const int w  = t >> 6;        // wave id
  const int l  = t & 63;        // lane in wave
  const int lm = l & 15;
  const int q  = l >> 4;
  const int r0 = w * 16;        // this wave's 16 V-phase rows

  // ---- P1: layer1 (K=2, dot2) -> HA ----
  {
    const int tx = t & 15, ty = t >> 4;   // rows tx+16i, cols ty*8..
    v2h wv[8]; float bb[8];
#pragma unroll
    for (int j = 0; j < 8; ++j){
      wv[j] = *(const v2h*)(g_w16 + OFF_F1W + (ty*8 + j)*2);
      bb[j] = f1b[ty*8 + j];
    }
#pragma unroll
    for (int i = 0; i < 4; ++i){
      const int r = tx + 16*i;
      int g = b*64 + r; if (g > NPTS-1) g = NPTS-1;
      const float2 xv = *(const float2*)(X + g*2);
      v2h xh; xh.x = (_Float16)xv.x; xh.y = (_Float16)xv.y;
      v8h hv;
#pragma unroll
      for (int j = 0; j < 8; ++j)
        hv[j] = (_Float16)lrelu(FDOT2(xh, wv[j], bb[j]));
      *(v8h*)(HA + r*128 + ((ty ^ (r & 15)) << 3)) = hv;
    }
  }
  __syncthreads();  // B1

  // ---- P2: MFMA layers f2..f5 ----
  layer_mfma(HA, HB, g_w16 + OFF_FW,         f2b, w, lm, q); __syncthreads(); // B2
  layer_mfma(HB, HA, g_w16 + OFF_FW + 16384, f3b, w, lm, q); __syncthreads(); // B3
  layer_mfma(HA, HB, g_w16 + OFF_FW + 32768, f4b, w, lm, q); __syncthreads(); // B4
  layer_mfma(HB, HA, g_w16 + OFF_FW + 49152, f5b, w, lm, q); __syncthreads(); // B5

  // ---- P3: per-wave head (rows r0..r0+16) + DS staging ----
  if (l < 32){
    const int r = r0 + (l >> 1), c = l & 1, rs = r & 15;
    float s = ffb[c];
    const v8h* wf = (const v8h*)(g_w16 + OFF_FFW + c*128);
#pragma unroll
    for (int ck = 0; ck < 16; ++ck){
      v8h h = *(const v8h*)(HA + r*128 + ((ck ^ rs) << 3));
      s = dot8(h, wf[ck], s);
    }
    FH[r*2 + c] = s;
  } else {
    const int idx = w*32 + (l - 32);
    int g = b*128 + idx; if (g > 2*NPTS-1) g = 2*NPTS-1;
    DS[idx] = X[g] - Xst[g];
  }
  __syncthreads();  // B6 — last barrier; Z buffers overlay HA/HB below

  // ================= V phase: fully wave-private =================
  const int j = l;

  // P4: z1 = srelu(Vl1 @ d)  (lane = channel j, 16 rows; swz(8) store)
  {
    const float w0 = (float)g_w16[OFF_VL1T + j];
    const float w1 = (float)g_w16[OFF_VL1T + 64 + j];
    const int cj = j >> 3, oj = j & 7;
#pragma unroll 4
    for (int rr = 0; rr < 16; ++rr){
      const int r = r0 + rr;
      const float a = fmaf(DS[2*r], w0, DS[2*r+1] * w1);
      Z1[r*64 + ((cj ^ (r & 7)) << 3) + oj] = (_Float16)srelu(a);
    }
  }

  // P5: z2 = srelu(V2x@d + V2z@z1), z3 = srelu(V3x@d + V3z@z2)  (MFMA)
  vfwd_mfma(Z1, Z2, g_w16 + OFF_V2Z, g_w16 + OFF_V2XT, DS, r0, lm, q);
  vfwd_mfma(Z2, Z3, g_w16 + OFF_V3Z, g_w16 + OFF_V3XT, DS, r0, lm, q);

  // P6: af, zf, V, sf  (lane per row)
  if (l < 16){
    const int r = r0 + l, rs = r & 7;
    float s = 0.f;
#pragma unroll
    for (int c = 0; c < 8; ++c){
      v8h z = *(const v8h*)(Z3 + r*64 + ((c ^ rs) << 3));
      v8h vf = *(const v8h*)(g_w16 + OFF_VFZ + c*8);
      s = dot8(z, vf, s);
    }
    const float d0 = DS[2*r], d1 = DS[2*r+1];
    const float af = fmaf(Vfx[0], d0, fmaf(Vfx[1], d1, s));
    const float zf = srelu(af);
    VV[r] = srelu(zf) + 0.01f * fmaf(d0, d0, d1*d1);
    SF[r] = sreluD(zf) * sreluD(af);
  }

  // P7: ga3 = sf * Vfz * srelu'(a3)  (in place over Z3; lane = j)
  {
    const float vf = (float)g_w16[OFF_VFZ + j];
    const int cj = j >> 3, oj = j & 7;
#pragma unroll 4
    for (int rr = 0; rr < 16; ++rr){
      const int r = r0 + rr;
      _Float16* p = Z3 + r*64 + ((cj ^ (r & 7)) << 3) + oj;
      const float z = (float)*p;
      *p = (_Float16)(SF[r] * vf * sreluD_from_z(z));
    }
  }

  // P8/P9: backward (in place, MFMA)
  vbwd_mfma(Z3, Z2, g_w16 + OFF_V3ZT, r0, lm, q);
  vbwd_mfma(Z2, Z1, g_w16 + OFF_V2ZT, r0, lm, q);

  // P10: gradV  (2 lanes per row)
  if (l < 32){
    const int r = r0 + (l >> 1), c = l & 1, rs = r & 7;
    float g = fmaf(0.02f, DS[2*r + c], SF[r] * Vfx[c]);
#pragma unroll
    for (int cc = 0; cc < 8; ++cc){
      const int sw = ((cc ^ rs) << 3);
      v8h g1 = *(const v8h*)(Z1 + r*64 + sw);
      v8h g2 = *(const v8h*)(Z2 + r*64 + sw);
      v8h g3 = *(const v8h*)(Z3 + r*64 + sw);
      v8h w1 = *(const v8h*)(g_w16 + OFF_VL1T + c*64 + cc*8);
      v8h w2 = *(const v8h*)(g_w16 + OFF_V2XT + c*64 + cc*8);
      v8h w3 = *(const v8h*)(g_w16 + OFF_V3XT + c*64 + cc*8);
      g = dot8(g1, w1, g);
      g = dot8(g2, w2, g);
      g = dot8(g3, w3, g);
    }
    GD[r*2 + c] = g;
  }

  // P11: epilogue (lane per row)
  if (l < 16){
    const int r = r0 + l;
    const int row = b*64 + r;
    if (row < NPTS){
      const float g0 = GD[2*r], g1 = GD[2*r+1];
      const float fh0 = FH[2*r], fh1 = FH[2*r+1];
      const float Vn  = fmaf(g0, g0, g1*g1);
      const float num = fmaf(0.1f, VV[r], fmaf(fh0, g0, fh1*g1));
      const float fm  = fmaxf(num, 0.f) / (Vn + 1e-10f);
      float2 o;
      o.x = fmaf(-g0, fm, fh0);
      o.y = fmaf(-g1, fm, fh1);
      *(float2*)(out + row*2) = o;
    }
  }
}

extern "C" void kernel_launch(void* const* d_in, const int* in_sizes, int n_in,
                              void* d_out, int out_size, void* d_ws, size_t ws_size,
                              hipStream_t stream)
{
  (void)d_ws; (void)ws_size; (void)n_in; (void)in_sizes; (void)out_size;
  const float* X   = (const float*)d_in[0];
  const float* Xst = (const float*)d_in[1];
  const float* Vl1 = (const float*)d_in[2];
  const float* V2x = (const float*)d_in[3];
  const float* V2z = (const float*)d_in[4];
  const float* V3x = (const float*)d_in[5];
  const float* V3z = (const float*)d_in[6];
  const float* Vfx = (const float*)d_in[7];
  const float* Vfz = (const float*)d_in[8];
  const float* f1w = (const float*)d_in[9];
  const float* f1b = (const float*)d_in[10];
  const float* f2w = (const float*)d_in[11];
  const float* f2b = (const float*)d_in[12];
  const float* f3w = (const float*)d_in[13];
  const float* f3b = (const float*)d_in[14];
  const float* f4w = (const float*)d_in[15];
  const float* f4b = (const float*)d_in[16];
  const float* f5w = (const float*)d_in[17];
  const float* f5b = (const float*)d_in[18];
  const float* ffw = (const float*)d_in[19];
  const float* ffb = (const float*)d_in[20];

  prep_kernel<<<(W16_TOTAL + 255)/256, 256, 0, stream>>>(
      f2w, f3w, f4w, f5w, V2z, V3z, Vl1, V2x, V3x, Vfz, ffw, f1w);
  icnn_main<<<NBLK, 256, 0, stream>>>(
      X, Xst, Vfx, f1b, f2b, f3b, f4b, f5b, ffb, (float*)d_out);
}

// Round 6
// 400.285 us; speedup vs baseline: 2.0563x; 1.0264x over previous
//
#include <hip/hip_runtime.h>

// ICNN_net_1503238553972 — round 6: occupancy push (LDS=32KB -> 5 blocks/CU,
// 20 waves) + all epilogue state in registers + head/zf/gradV as wave-private
// MFMAs. 5 barriers (f_hat phase only); V phase barrier-free, wave-private.
// Z1/Z2 overlay the wave's own HA rows (read by the head MFMA first, in-order
// within the wave), Z3 overlays the wave's own HB rows (dead after f5).
// A-fragments with only-row-0/1 meaningful read finite junk (g_w16 zero-padded)
// into unused D rows. sf is deferred through the linear backward and applied
// once in the gradV epilogue.

typedef _Float16 v2h __attribute__((ext_vector_type(2)));
typedef _Float16 v4h __attribute__((ext_vector_type(4)));
typedef _Float16 v8h __attribute__((ext_vector_type(8)));
typedef float    v4f __attribute__((ext_vector_type(4)));

#define NPTS 500000
#define NBLK ((NPTS + 63) / 64)   // 7813

// offsets in halves inside g_w16
#define OFF_FW    0               // f2..f5: L*16384, [o*128+k]
#define OFF_V2Z   65536           // [j*64+k]
#define OFF_V3Z   69632
#define OFF_V2ZT  73728           // [k*64+j]
#define OFF_V3ZT  77824
#define OFF_VL1T  81920           // [c*64+j]
#define OFF_V2XT  82048
#define OFF_V3XT  82176
#define OFF_VFZ   82304           // [64]
#define OFF_FFW   82368           // [c*128+k]
#define OFF_F1W   82624           // [oc*2+c]
#define W16_DATA  82880
#define W16_TOTAL (W16_DATA + 2048)   // zero pad: junk A-rows stay in-bounds

__device__ __align__(16) _Float16 g_w16[W16_TOTAL];

#if defined(__has_builtin)
#if __has_builtin(__builtin_amdgcn_fdot2)
#define FDOT2(a,b,c) __builtin_amdgcn_fdot2((a),(b),(c),false)
#endif
#endif
#ifndef FDOT2
__device__ __forceinline__ float fdot2_fb(v2h a, v2h b, float c){
  return fmaf((float)a.x, (float)b.x, fmaf((float)a.y, (float)b.y, c));
}
#define FDOT2(a,b,c) fdot2_fb((a),(b),(c))
#endif

__device__ __forceinline__ float srelu(float x){
  float c = fminf(fmaxf(x, 0.f), 1.f);
  return c * fmaf(-0.5f, c, x);
}
__device__ __forceinline__ float sreluD(float x){
  return fminf(fmaxf(x, 0.f), 1.f);
}
__device__ __forceinline__ float lrelu(float x){
  return fmaxf(x, 0.01f * x);
}
__device__ __forceinline__ float sreluD_from_z(float z){
  return fminf(sqrtf(2.f * z), 1.f);
}

// ---------------- prep: fp32 weights -> f16 layouts (+zero pad) ----------------
__global__ __launch_bounds__(256) void prep_kernel(
  const float* __restrict__ f2w, const float* __restrict__ f3w,
  const float* __restrict__ f4w, const float* __restrict__ f5w,
  const float* __restrict__ V2z, const float* __restrict__ V3z,
  const float* __restrict__ Vl1, const float* __restrict__ V2x,
  const float* __restrict__ V3x, const float* __restrict__ Vfz,
  const float* __restrict__ ffw, const float* __restrict__ f1w)
{
  const int i = blockIdx.x * 256 + threadIdx.x;
  if (i >= W16_TOTAL) return;
  if (i >= W16_DATA){ g_w16[i] = (_Float16)0.f; return; }
  float v;
  if (i < 65536){
    const float* W[4] = {f2w, f3w, f4w, f5w};
    v = W[i >> 14][i & 16383];
  } else if (i < 69632)  v = V2z[i - 65536];
  else if (i < 73728)    v = V3z[i - 69632];
  else if (i < 77824){ int r = i - 73728; v = V2z[(r & 63)*64 + (r >> 6)]; }
  else if (i < 81920){ int r = i - 77824; v = V3z[(r & 63)*64 + (r >> 6)]; }
  else if (i < 82048){ int r = i - 81920; v = Vl1[(r & 63)*2 + (r >> 6)]; }
  else if (i < 82176){ int r = i - 82048; v = V2x[(r & 63)*2 + (r >> 6)]; }
  else if (i < 82304){ int r = i - 82176; v = V3x[(r & 63)*2 + (r >> 6)]; }
  else if (i < 82368)    v = Vfz[i - 82304];
  else if (i < 82624)    v = ffw[i - 82368];
  else                   v = f1w[i - 82624];
  g_w16[i] = (_Float16)v;
}

// ---------------- f_hat MFMA layer: 128->128, 64 rows, wave=32 out-ch ----------------
__device__ __forceinline__ void layer_mfma(const _Float16* hin, _Float16* hout,
    const _Float16* __restrict__ Wl, const float* __restrict__ Bp,
    int w, int lm, int q)
{
  v4f acc[2][4];
#pragma unroll
  for (int mt = 0; mt < 2; ++mt)
#pragma unroll
    for (int nt = 0; nt < 4; ++nt) acc[mt][nt] = (v4f){0.f,0.f,0.f,0.f};

#pragma unroll
  for (int kt = 0; kt < 4; ++kt){
    const int sw = ((kt*4 + q) ^ lm) << 3;
    v8h A0 = *(const v8h*)(Wl + (w*32      + lm)*128 + kt*32 + q*8);
    v8h A1 = *(const v8h*)(Wl + (w*32 + 16 + lm)*128 + kt*32 + q*8);
    v8h B0 = *(const v8h*)(hin + (     lm)*128 + sw);
    v8h B1 = *(const v8h*)(hin + (16 + lm)*128 + sw);
    v8h B2 = *(const v8h*)(hin + (32 + lm)*128 + sw);
    v8h B3 = *(const v8h*)(hin + (48 + lm)*128 + sw);
    acc[0][0] = __builtin_amdgcn_mfma_f32_16x16x32_f16(A0, B0, acc[0][0], 0,0,0);
    acc[0][1] = __builtin_amdgcn_mfma_f32_16x16x32_f16(A0, B1, acc[0][1], 0,0,0);
    acc[0][2] = __builtin_amdgcn_mfma_f32_16x16x32_f16(A0, B2, acc[0][2], 0,0,0);
    acc[0][3] = __builtin_amdgcn_mfma_f32_16x16x32_f16(A0, B3, acc[0][3], 0,0,0);
    acc[1][0] = __builtin_amdgcn_mfma_f32_16x16x32_f16(A1, B0, acc[1][0], 0,0,0);
    acc[1][1] = __builtin_amdgcn_mfma_f32_16x16x32_f16(A1, B1, acc[1][1], 0,0,0);
    acc[1][2] = __builtin_amdgcn_mfma_f32_16x16x32_f16(A1, B2, acc[1][2], 0,0,0);
    acc[1][3] = __builtin_amdgcn_mfma_f32_16x16x32_f16(A1, B3, acc[1][3], 0,0,0);
  }

#pragma unroll
  for (int mt = 0; mt < 2; ++mt){
    const int o0 = w*32 + mt*16 + q*4;
    const v4f bv = *(const v4f*)(Bp + o0);
    const int coff = (((o0 >> 3) ^ lm) << 3) + (o0 & 7);
#pragma unroll
    for (int nt = 0; nt < 4; ++nt){
      const int r = nt*16 + lm;
      v4h hv;
      hv[0] = (_Float16)lrelu(acc[mt][nt][0] + bv[0]);
      hv[1] = (_Float16)lrelu(acc[mt][nt][1] + bv[1]);
      hv[2] = (_Float16)lrelu(acc[mt][nt][2] + bv[2]);
      hv[3] = (_Float16)lrelu(acc[mt][nt][3] + bv[3]);
      *(v4h*)(hout + r*128 + coff) = hv;
    }
  }
}

// ---------------- V-net fwd layer (wave-private arena, 16 rows) ----------------
__device__ __forceinline__ void vfwd_mfma(const _Float16* zin, _Float16* zout,
    const _Float16* __restrict__ Wz,   // [64][64] row-major
    const _Float16* __restrict__ WxT,  // [2][64]
    float d0, float d1, int lm, int q)
{
  v4f acc[4];
#pragma unroll
  for (int mt = 0; mt < 4; ++mt) acc[mt] = (v4f){0.f,0.f,0.f,0.f};
  const int rs = lm & 7;
#pragma unroll
  for (int kt = 0; kt < 2; ++kt){
    v8h B = *(const v8h*)(zin + lm*64 + (((kt*4 + q) ^ rs) << 3));
#pragma unroll
    for (int mt = 0; mt < 4; ++mt){
      v8h A = *(const v8h*)(Wz + (mt*16 + lm)*64 + kt*32 + q*8);
      acc[mt] = __builtin_amdgcn_mfma_f32_16x16x32_f16(A, B, acc[mt], 0,0,0);
    }
  }
#pragma unroll
  for (int mt = 0; mt < 4; ++mt){
    const int o0 = mt*16 + q*4;
    v4h hv;
#pragma unroll
    for (int reg = 0; reg < 4; ++reg){
      const int o = o0 + reg;
      const float v = acc[mt][reg] + (float)WxT[o]*d0 + (float)WxT[64 + o]*d1;
      hv[reg] = (_Float16)srelu(v);
    }
    *(v4h*)(zout + lm*64 + (((o0 >> 3) ^ rs) << 3) + (o0 & 7)) = hv;
  }
}

// ---------------- V-net bwd layer (wave-private arena, in-place) ----------------
__device__ __forceinline__ void vbwd_mfma(const _Float16* gin, _Float16* zio,
    const _Float16* __restrict__ WT,   // [64][64] = W^T row-major [k][j]
    int lm, int q)
{
  v4f acc[4];
#pragma unroll
  for (int mt = 0; mt < 4; ++mt) acc[mt] = (v4f){0.f,0.f,0.f,0.f};
  const int rs = lm & 7;
#pragma unroll
  for (int kt = 0; kt < 2; ++kt){
    v8h B = *(const v8h*)(gin + lm*64 + (((kt*4 + q) ^ rs) << 3));
#pragma unroll
    for (int mt = 0; mt < 4; ++mt){
      v8h A = *(const v8h*)(WT + (mt*16 + lm)*64 + kt*32 + q*8);
      acc[mt] = __builtin_amdgcn_mfma_f32_16x16x32_f16(A, B, acc[mt], 0,0,0);
    }
  }
#pragma unroll
  for (int mt = 0; mt < 4; ++mt){
    const int k0 = mt*16 + q*4;
    _Float16* p = zio + lm*64 + (((k0 >> 3) ^ rs) << 3) + (k0 & 7);
    v4h zv = *(const v4h*)p;
    v4h gv;
#pragma unroll
    for (int reg = 0; reg < 4; ++reg)
      gv[reg] = (_Float16)(acc[mt][reg] * sreluD_from_z((float)zv[reg]));
    *(v4h*)p = gv;
  }
}

// ---------------- main ----------------
__global__ __launch_bounds__(256, 5) void icnn_main(
  const float* __restrict__ X, const float* __restrict__ Xst,
  const float* __restrict__ Vfx,
  const float* __restrict__ f1b, const float* __restrict__ f2b,
  const float* __restrict__ f3b, const float* __restrict__ f4b,
  const float* __restrict__ f5b, const float* __restrict__ ffb,
  float* __restrict__ out)
{
  __shared__ __align__(16) char smem[32768];       // exactly 32KB -> 5 blocks/CU
  _Float16* const HA = (_Float16*)smem;            // [64][128] f16 swz16
  _Float16* const HB = (_Float16*)(smem + 16384);  // [64][128]

  const int t  = threadIdx.x;
  const int b  = blockIdx.x;
  const int w  = t >> 6;        // wave id
  const int l  = t & 63;        // lane in wave
  const int lm = l & 15;
  const int q  = l >> 4;
  const int r0 = w * 16;        // this wave's 16 V-phase rows

  // wave-private arenas (own HA rows for Z1/Z2, own HB rows for Z3)
  _Float16* const Z1 = HA + w*2048;          // [16][64] swz8
  _Float16* const Z2 = Z1 + 1024;
  _Float16* const Z3 = HB + w*2048;

  // ---- P1: layer1 (K=2, dot2) -> HA ----
  {
    const int tx = t & 15, ty = t >> 4;
    v2h wv[8]; float bb[8];
#pragma unroll
    for (int j = 0; j < 8; ++j){
      wv[j] = *(const v2h*)(g_w16 + OFF_F1W + (ty*8 + j)*2);
      bb[j] = f1b[ty*8 + j];
    }
#pragma unroll
    for (int i = 0; i < 4; ++i){
      const int r = tx + 16*i;
      int g = b*64 + r; if (g > NPTS-1) g = NPTS-1;
      const float2 xv = *(const float2*)(X + g*2);
      v2h xh; xh.x = (_Float16)xv.x; xh.y = (_Float16)xv.y;
      v8h hv;
#pragma unroll
      for (int j = 0; j < 8; ++j)
        hv[j] = (_Float16)lrelu(FDOT2(xh, wv[j], bb[j]));
      *(v8h*)(HA + r*128 + ((ty ^ (r & 15)) << 3)) = hv;
    }
  }
  __syncthreads();  // B1

  // ---- P2: MFMA layers f2..f5 ----
  layer_mfma(HA, HB, g_w16 + OFF_FW,         f2b, w, lm, q); __syncthreads(); // B2
  layer_mfma(HB, HA, g_w16 + OFF_FW + 16384, f3b, w, lm, q); __syncthreads(); // B3
  layer_mfma(HA, HB, g_w16 + OFF_FW + 32768, f4b, w, lm, q); __syncthreads(); // B4
  layer_mfma(HB, HA, g_w16 + OFF_FW + 49152, f5b, w, lm, q); __syncthreads(); // B5 (last)

  // ================= V phase: wave-private, barrier-free =================
  const int rs = lm & 7;

  // P3: head via MFMA — fh = ffw @ h5 (rows r0..r0+15, own HA rows)
  v4f aF = (v4f){0.f,0.f,0.f,0.f};
  {
    const int rh = r0 + lm, rhs = rh & 15;
#pragma unroll
    for (int kt = 0; kt < 4; ++kt){
      v8h A = *(const v8h*)(g_w16 + OFF_FFW + lm*128 + kt*32 + q*8);
      v8h B = *(const v8h*)(HA + rh*128 + (((kt*4 + q) ^ rhs) << 3));
      aF = __builtin_amdgcn_mfma_f32_16x16x32_f16(A, B, aF, 0,0,0);
    }
  }

  // d for this lane's row (replicated across q)
  const int rowi = b*64 + r0 + lm;
  const int rc = rowi < NPTS ? rowi : NPTS-1;
  const float2 xx = *(const float2*)(X  + rc*2);
  const float2 xs = *(const float2*)(Xst + rc*2);
  const float d0 = xx.x - xs.x, d1 = xx.y - xs.y;
  const float vfx0 = Vfx[0], vfx1 = Vfx[1];

  // P4: z1 = srelu(Vl1 @ d)  (lane = (row lm, ch-block q))
  {
    v8h w0a = *(const v8h*)(g_w16 + OFF_VL1T + q*16);
    v8h w0b = *(const v8h*)(g_w16 + OFF_VL1T + q*16 + 8);
    v8h w1a = *(const v8h*)(g_w16 + OFF_VL1T + 64 + q*16);
    v8h w1b = *(const v8h*)(g_w16 + OFF_VL1T + 64 + q*16 + 8);
    v8h za, zb;
#pragma unroll
    for (int j = 0; j < 8; ++j){
      za[j] = (_Float16)srelu(fmaf(d0, (float)w0a[j], d1 * (float)w1a[j]));
      zb[j] = (_Float16)srelu(fmaf(d0, (float)w0b[j], d1 * (float)w1b[j]));
    }
    *(v8h*)(Z1 + lm*64 + (((q*2    ) ^ rs) << 3)) = za;
    *(v8h*)(Z1 + lm*64 + (((q*2 + 1) ^ rs) << 3)) = zb;
  }

  // P5: z2, z3 (wave-private MFMA)
  vfwd_mfma(Z1, Z2, g_w16 + OFF_V2Z, g_w16 + OFF_V2XT, d0, d1, lm, q);
  vfwd_mfma(Z2, Z3, g_w16 + OFF_V3Z, g_w16 + OFF_V3XT, d0, d1, lm, q);

  // P6: zf head via MFMA (row 0 of A = Vfz); af/V/sf in regs (valid on q==0)
  float VVr, sf;
  {
    v4f aS = (v4f){0.f,0.f,0.f,0.f};
#pragma unroll
    for (int kt = 0; kt < 2; ++kt){
      v8h A = *(const v8h*)(g_w16 + OFF_VFZ + lm*64 + kt*32 + q*8);
      v8h B = *(const v8h*)(Z3 + lm*64 + (((kt*4 + q) ^ rs) << 3));
      aS = __builtin_amdgcn_mfma_f32_16x16x32_f16(A, B, aS, 0,0,0);
    }
    const float af = fmaf(vfx0, d0, fmaf(vfx1, d1, aS[0]));
    const float zf = srelu(af);
    VVr = srelu(zf) + 0.01f * fmaf(d0, d0, d1*d1);
    sf  = sreluD(zf) * sreluD(af);
  }

  // P7: u3 = Vfz * srelu'(a3)  (sf deferred; in place over Z3; 2 b128 RMW/lane)
#pragma unroll
  for (int cc = 0; cc < 2; ++cc){
    const int c = q*2 + cc;
    _Float16* p = Z3 + lm*64 + ((c ^ rs) << 3);
    v8h z  = *(const v8h*)p;
    v8h vf = *(const v8h*)(g_w16 + OFF_VFZ + c*8);
    v8h u;
#pragma unroll
    for (int j = 0; j < 8; ++j)
      u[j] = (_Float16)((float)vf[j] * sreluD_from_z((float)z[j]));
    *(v8h*)p = u;
  }

  // P8/P9: backward (in place, wave-private MFMA); sf still deferred
  vbwd_mfma(Z3, Z2, g_w16 + OFF_V3ZT, lm, q);
  vbwd_mfma(Z2, Z1, g_w16 + OFF_V2ZT, lm, q);

  // P10: gradV via MFMA over 3 buffers (rows 0/1 of A = Wx^T); apply sf once
  float g0, g1;
  {
    v4f aG = (v4f){0.f,0.f,0.f,0.f};
    const _Float16* Zs[3]   = {Z1, Z2, Z3};
    const int       Ws[3]   = {OFF_VL1T, OFF_V2XT, OFF_V3XT};
#pragma unroll
    for (int li = 0; li < 3; ++li){
#pragma unroll
      for (int kt = 0; kt < 2; ++kt){
        v8h A = *(const v8h*)(g_w16 + Ws[li] + lm*64 + kt*32 + q*8);
        v8h B = *(const v8h*)(Zs[li] + lm*64 + (((kt*4 + q) ^ rs) << 3));
        aG = __builtin_amdgcn_mfma_f32_16x16x32_f16(A, B, aG, 0,0,0);
      }
    }
    g0 = fmaf(0.02f, d0, sf * (vfx0 + aG[0]));
    g1 = fmaf(0.02f, d1, sf * (vfx1 + aG[1]));
  }

  // P11: epilogue (q==0 lanes hold everything in regs)
  if (q == 0 && rowi < NPTS){
    const float fh0 = aF[0] + ffb[0];
    const float fh1 = aF[1] + ffb[1];
    const float Vn  = fmaf(g0, g0, g1*g1);
    const float num = fmaf(0.1f, VVr, fmaf(fh0, g0, fh1*g1));
    const float fm  = fmaxf(num, 0.f) / (Vn + 1e-10f);
    float2 o;
    o.x = fmaf(-g0, fm, fh0);
    o.y = fmaf(-g1, fm, fh1);
    *(float2*)(out + rowi*2) = o;
  }
}

extern "C" void kernel_launch(void* const* d_in, const int* in_sizes, int n_in,
                              void* d_out, int out_size, void* d_ws, size_t ws_size,
                              hipStream_t stream)
{
  (void)d_ws; (void)ws_size; (void)n_in; (void)in_sizes; (void)out_size;
  const float* X   = (const float*)d_in[0];
  const float* Xst = (const float*)d_in[1];
  const float* Vl1 = (const float*)d_in[2];
  const float* V2x = (const float*)d_in[3];
  const float* V2z = (const float*)d_in[4];
  const float* V3x = (const float*)d_in[5];
  const float* V3z = (const float*)d_in[6];
  const float* Vfx = (const float*)d_in[7];
  const float* Vfz = (const float*)d_in[8];
  const float* f1w = (const float*)d_in[9];
  const float* f1b = (const float*)d_in[10];
  const float* f2w = (const float*)d_in[11];
  const float* f2b = (const float*)d_in[12];
  const float* f3w = (const float*)d_in[13];
  const float* f3b = (const float*)d_in[14];
  const float* f4w = (const float*)d_in[15];
  const float* f4b = (const float*)d_in[16];
  const float* f5w = (const float*)d_in[17];
  const float* f5b = (const float*)d_in[18];
  const float* ffw = (const float*)d_in[19];
  const float* ffb = (const float*)d_in[20];

  prep_kernel<<<(W16_TOTAL + 255)/256, 256, 0, stream>>>(
      f2w, f3w, f4w, f5w, V2z, V3z, Vl1, V2x, V3x, Vfz, ffw, f1w);
  icnn_main<<<NBLK, 256, 0, stream>>>(
      X, Xst, Vfx, f1b, f2b, f3b, f4b, f5b, ffb, (float*)d_out);
}